// Round 1
// baseline (141.503 us; speedup 1.0000x reference)
//
#include <hip/hip_runtime.h>
#include <hip/hip_bf16.h>
#include <stdint.h>

typedef __bf16 bf16;
typedef __bf16 bf16x8 __attribute__((ext_vector_type(8)));
typedef __bf16 bf16x4 __attribute__((ext_vector_type(4)));
typedef float  f32x4  __attribute__((ext_vector_type(4)));

#define MFMA(a,b,c) __builtin_amdgcn_mfma_f32_16x16x32_bf16((a),(b),(c),0,0,0)

__device__ __forceinline__ void gload_lds16(const void* g, void* lds) {
  __builtin_amdgcn_global_load_lds(
      (const __attribute__((address_space(1))) uint32_t*)g,
      (__attribute__((address_space(3))) uint32_t*)lds, 16, 0, 0);
}

// ---------------- convert fp32 -> bf16 (x + 4 weights) ----------------
__global__ __launch_bounds__(256) void k_cvt(
    const float* __restrict__ x,
    const float* __restrict__ wq, const float* __restrict__ wk,
    const float* __restrict__ wv, const float* __restrict__ wo,
    bf16* __restrict__ xb, bf16* __restrict__ wqb, bf16* __restrict__ wkb,
    bf16* __restrict__ wvb, bf16* __restrict__ wob)
{
  int r = blockIdx.y;
  const float* s; bf16* d; int n;
  switch (r) {
    case 0: s = x;  d = xb;  n = 4194304; break;
    case 1: s = wq; d = wqb; n = 1048576; break;
    case 2: s = wk; d = wkb; n = 1048576; break;
    case 3: s = wv; d = wvb; n = 1048576; break;
    default: s = wo; d = wob; n = 1048576; break;
  }
  int i = (blockIdx.x * 256 + threadIdx.x) * 8;
  if (i >= n) return;
  const float4* sp = (const float4*)(s + i);
  float4 a = sp[0], b = sp[1];
  bf16x8 o;
  o[0]=(bf16)a.x; o[1]=(bf16)a.y; o[2]=(bf16)a.z; o[3]=(bf16)a.w;
  o[4]=(bf16)b.x; o[5]=(bf16)b.y; o[6]=(bf16)b.z; o[7]=(bf16)b.w;
  *(bf16x8*)(d + i) = o;
}

// ---------------- fused QKV projection GEMM ----------------
// C[m][f] = sum_k A[m][k]*W[f][k] + bias[f];  M=4096, F=3*1024, K=1024
// Q written scaled by 1/32 into [b,h,n,d]; K into [b,h,n,d]; V into [b,h,d,n].
__global__ __launch_bounds__(256) void k_gemm_qkv(
    const bf16* __restrict__ A,
    const bf16* __restrict__ Wq, const bf16* __restrict__ Wk, const bf16* __restrict__ Wv,
    const float* __restrict__ bq, const float* __restrict__ bk, const float* __restrict__ bv,
    bf16* __restrict__ Qw, bf16* __restrict__ Kw, bf16* __restrict__ Vtw)
{
  __shared__ __align__(16) char As[8192];
  __shared__ __align__(16) char Bs[8192];
  int tid = threadIdx.x;
  int wv4 = tid >> 6, l = tid & 63, lo = l & 15, hi = l >> 4;
  int mt = blockIdx.x;           // 0..31
  int ft = blockIdx.y;           // 0..23
  int wsel = ft >> 3;
  const bf16* W = (wsel == 0) ? Wq : (wsel == 1) ? Wk : Wv;
  const float* bias = (wsel == 0) ? bq : (wsel == 1) ? bk : bv;
  int f0 = (ft & 7) * 128;
  const bf16* Ab = A + (size_t)mt * 128 * 1024;
  const bf16* Wb = W + (size_t)f0 * 1024;
  int wm = wv4 >> 1, wf = wv4 & 1;
  f32x4 acc[4][4];
  #pragma unroll
  for (int i = 0; i < 4; i++)
    #pragma unroll
    for (int j = 0; j < 4; j++) acc[i][j] = (f32x4){0.f, 0.f, 0.f, 0.f};

  for (int k0 = 0; k0 < 1024; k0 += 32) {
    __syncthreads();
    #pragma unroll
    for (int p = 0; p < 2; p++) {
      int e = p * 256 + tid;
      int row = e >> 2, sl = e & 3;
      gload_lds16(Ab + row * 1024 + k0 + sl * 8, As + (p * 256 + wv4 * 64) * 16);
      gload_lds16(Wb + row * 1024 + k0 + sl * 8, Bs + (p * 256 + wv4 * 64) * 16);
    }
    __syncthreads();
    bf16x8 af[4], bfr[4];
    #pragma unroll
    for (int ms = 0; ms < 4; ms++)
      af[ms] = *(const bf16x8*)(As + ((wm * 64 + ms * 16 + lo) * 32 + hi * 8) * 2);
    #pragma unroll
    for (int fs = 0; fs < 4; fs++)
      bfr[fs] = *(const bf16x8*)(Bs + ((wf * 64 + fs * 16 + lo) * 32 + hi * 8) * 2);
    #pragma unroll
    for (int ms = 0; ms < 4; ms++)
      #pragma unroll
      for (int fs = 0; fs < 4; fs++)
        acc[ms][fs] = MFMA(af[ms], bfr[fs], acc[ms][fs]);
  }

  float bv4[4];
  #pragma unroll
  for (int fs = 0; fs < 4; fs++) bv4[fs] = bias[f0 + wf * 64 + fs * 16 + lo];
  #pragma unroll
  for (int ms = 0; ms < 4; ms++) {
    #pragma unroll
    for (int fs = 0; fs < 4; fs++) {
      int fl = f0 + wf * 64 + fs * 16 + lo;
      int h = fl >> 6, dd = fl & 63;
      #pragma unroll
      for (int r = 0; r < 4; r++) {
        int m = mt * 128 + wm * 64 + ms * 16 + hi * 4 + r;
        int b = m >> 11, n = m & 2047;
        float val = acc[ms][fs][r] + bv4[fs];
        if (wsel == 0)      Qw[(((size_t)(b * 16 + h) * 2048 + n) * 64) + dd] = (bf16)(val * 0.03125f);
        else if (wsel == 1) Kw[(((size_t)(b * 16 + h) * 2048 + n) * 64) + dd] = (bf16)val;
        else                Vtw[(((size_t)(b * 16 + h) * 64 + dd) * 2048) + n] = (bf16)val;
      }
    }
  }
}

// ---------------- flash attention ----------------
// Q pre-scaled by 1/32. S^T = K*Q^T (swapped) so each lane's q-row is lane&15.
__global__ __launch_bounds__(256) void k_attn(
    const bf16* __restrict__ Q, const bf16* __restrict__ K,
    const bf16* __restrict__ Vt, bf16* __restrict__ O)
{
  __shared__ __align__(16) char Ks[8192];
  __shared__ __align__(16) char Vs[8192];
  __shared__ __align__(16) char Ps[4 * 16 * 176];
  int tid = threadIdx.x;
  int wv4 = tid >> 6, l = tid & 63, lo = l & 15, hi = l >> 4;
  int qt = blockIdx.x, bh = blockIdx.y;
  const bf16* Qb = Q + ((size_t)bh * 2048 + qt * 64 + wv4 * 16) * 64;
  const bf16* Kb = K + (size_t)bh * 2048 * 64;
  const bf16* Vb = Vt + (size_t)bh * 64 * 2048;

  bf16x8 qf[2];
  #pragma unroll
  for (int c = 0; c < 2; c++)
    qf[c] = *(const bf16x8*)(Qb + lo * 64 + c * 32 + hi * 8);

  f32x4 oacc[4];
  #pragma unroll
  for (int ds = 0; ds < 4; ds++) oacc[ds] = (f32x4){0.f, 0.f, 0.f, 0.f};
  float m_run = -3.0e38f, l_run = 0.f;

  int r0 = tid >> 3;        // staging row 0..31
  int sl8 = tid & 7;        // 16B slot within 128B row
  char* Pw = Ps + wv4 * 2816 + lo * 176;

  uint4 kst0, kst1, vst0, vst1;
  #define STAGE(t) {                                                     \
    kst0 = *(const uint4*)(Kb + (size_t)(t) * 4096 + tid * 8);           \
    kst1 = *(const uint4*)(Kb + (size_t)(t) * 4096 + 2048 + tid * 8);    \
    vst0 = *(const uint4*)(Vb + (size_t)r0 * 2048 + (t) * 64 + sl8 * 8); \
    vst1 = *(const uint4*)(Vb + (size_t)(r0 + 32) * 2048 + (t) * 64 + sl8 * 8); }

  STAGE(0);
  for (int t = 0; t < 32; ++t) {
    __syncthreads();
    int sw = 16 * (sl8 ^ (r0 & 7));
    *(uint4*)(Ks + r0 * 128 + sw)        = kst0;
    *(uint4*)(Ks + (r0 + 32) * 128 + sw) = kst1;
    *(uint4*)(Vs + r0 * 128 + sw)        = vst0;
    *(uint4*)(Vs + (r0 + 32) * 128 + sw) = vst1;
    __syncthreads();
    if (t < 31) STAGE(t + 1);

    // S^T = K * Q^T   (16 q cols, 64 k rows, contraction d=64)
    f32x4 s[4];
    #pragma unroll
    for (int ks = 0; ks < 4; ks++) s[ks] = (f32x4){0.f, 0.f, 0.f, 0.f};
    #pragma unroll
    for (int c = 0; c < 2; c++)
      #pragma unroll
      for (int ks = 0; ks < 4; ks++) {
        int krow = ks * 16 + lo;
        bf16x8 kf = *(const bf16x8*)(Ks + krow * 128 + 16 * ((hi + 4 * c) ^ (krow & 7)));
        s[ks] = MFMA(kf, qf[c], s[ks]);
      }

    // online softmax over the q-row (lane-local + 4-lane group reduce)
    float tmax = -3.0e38f;
    #pragma unroll
    for (int ks = 0; ks < 4; ks++)
      #pragma unroll
      for (int r = 0; r < 4; r++) tmax = fmaxf(tmax, s[ks][r]);
    tmax = fmaxf(tmax, __shfl_xor(tmax, 16));
    tmax = fmaxf(tmax, __shfl_xor(tmax, 32));
    float mnew = fmaxf(m_run, tmax);
    float alpha = __expf(m_run - mnew);
    float tsum = 0.f;
    #pragma unroll
    for (int ks = 0; ks < 4; ks++) {
      bf16x4 pb;
      #pragma unroll
      for (int r = 0; r < 4; r++) {
        float p = __expf(s[ks][r] - mnew);
        tsum += p;
        pb[r] = (bf16)p;
      }
      *(bf16x4*)(Pw + ks * 32 + hi * 8) = pb;
    }
    tsum += __shfl_xor(tsum, 16);
    tsum += __shfl_xor(tsum, 32);
    l_run = l_run * alpha + tsum;
    m_run = mnew;
    #pragma unroll
    for (int ds = 0; ds < 4; ds++) oacc[ds] *= alpha;

    // O^T += V^T * P^T  (rows d, cols q)
    #pragma unroll
    for (int c = 0; c < 2; c++) {
      bf16x8 pf = *(const bf16x8*)(Pw + c * 64 + hi * 16);
      #pragma unroll
      for (int ds = 0; ds < 4; ds++) {
        int drow = ds * 16 + lo;
        bf16x8 vf = *(const bf16x8*)(Vs + drow * 128 + 16 * ((hi + 4 * c) ^ (drow & 7)));
        oacc[ds] = MFMA(vf, pf, oacc[ds]);
      }
    }
  }
  #undef STAGE

  float inv = 1.0f / l_run;
  int b = bh >> 4, h = bh & 15;
  int n = qt * 64 + wv4 * 16 + lo;
  #pragma unroll
  for (int ds = 0; ds < 4; ds++) {
    bf16x4 ob;
    #pragma unroll
    for (int r = 0; r < 4; r++) ob[r] = (bf16)(oacc[ds][r] * inv);
    *(bf16x4*)(O + ((size_t)(b * 2048 + n)) * 1024 + h * 64 + ds * 16 + hi * 4) = ob;
  }
}

// ---------------- output projection GEMM ----------------
__global__ __launch_bounds__(256) void k_gemm_out(
    const bf16* __restrict__ A,      // O [4096][1024] bf16
    const bf16* __restrict__ W,      // Wo bf16 [1024][1024]
    const float* __restrict__ bias,  // bo
    float* __restrict__ Cout)        // [4096][1024] fp32
{
  __shared__ __align__(16) char As[8192];
  __shared__ __align__(16) char Bs[8192];
  int tid = threadIdx.x;
  int wv4 = tid >> 6, l = tid & 63, lo = l & 15, hi = l >> 4;
  int mt = blockIdx.x;           // 0..31
  int f0 = blockIdx.y * 128;     // 0..7 tiles
  const bf16* Ab = A + (size_t)mt * 128 * 1024;
  const bf16* Wb = W + (size_t)f0 * 1024;
  int wm = wv4 >> 1, wf = wv4 & 1;
  f32x4 acc[4][4];
  #pragma unroll
  for (int i = 0; i < 4; i++)
    #pragma unroll
    for (int j = 0; j < 4; j++) acc[i][j] = (f32x4){0.f, 0.f, 0.f, 0.f};

  for (int k0 = 0; k0 < 1024; k0 += 32) {
    __syncthreads();
    #pragma unroll
    for (int p = 0; p < 2; p++) {
      int e = p * 256 + tid;
      int row = e >> 2, sl = e & 3;
      gload_lds16(Ab + row * 1024 + k0 + sl * 8, As + (p * 256 + wv4 * 64) * 16);
      gload_lds16(Wb + row * 1024 + k0 + sl * 8, Bs + (p * 256 + wv4 * 64) * 16);
    }
    __syncthreads();
    bf16x8 af[4], bfr[4];
    #pragma unroll
    for (int ms = 0; ms < 4; ms++)
      af[ms] = *(const bf16x8*)(As + ((wm * 64 + ms * 16 + lo) * 32 + hi * 8) * 2);
    #pragma unroll
    for (int fs = 0; fs < 4; fs++)
      bfr[fs] = *(const bf16x8*)(Bs + ((wf * 64 + fs * 16 + lo) * 32 + hi * 8) * 2);
    #pragma unroll
    for (int ms = 0; ms < 4; ms++)
      #pragma unroll
      for (int fs = 0; fs < 4; fs++)
        acc[ms][fs] = MFMA(af[ms], bfr[fs], acc[ms][fs]);
  }

  float bv4[4];
  #pragma unroll
  for (int fs = 0; fs < 4; fs++) bv4[fs] = bias[f0 + wf * 64 + fs * 16 + lo];
  #pragma unroll
  for (int ms = 0; ms < 4; ms++)
    #pragma unroll
    for (int fs = 0; fs < 4; fs++) {
      int f = f0 + wf * 64 + fs * 16 + lo;
      #pragma unroll
      for (int r = 0; r < 4; r++) {
        int m = mt * 128 + wm * 64 + ms * 16 + hi * 4 + r;
        Cout[(size_t)m * 1024 + f] = acc[ms][fs][r] + bv4[fs];
      }
    }
}

// ---------------- launch ----------------
extern "C" void kernel_launch(void* const* d_in, const int* in_sizes, int n_in,
                              void* d_out, int out_size, void* d_ws, size_t ws_size,
                              hipStream_t stream) {
  const float* x  = (const float*)d_in[0];
  const float* Wq = (const float*)d_in[1];
  const float* bq = (const float*)d_in[2];
  const float* Wk = (const float*)d_in[3];
  const float* bk = (const float*)d_in[4];
  const float* Wv = (const float*)d_in[5];
  const float* bv = (const float*)d_in[6];
  const float* Wo = (const float*)d_in[7];
  const float* bo = (const float*)d_in[8];
  float* out = (float*)d_out;
  char* ws = (char*)d_ws;

  bf16* xb  = (bf16*)(ws);
  bf16* wqb = (bf16*)(ws + 8388608);
  bf16* wkb = (bf16*)(ws + 10485760);
  bf16* wvb = (bf16*)(ws + 12582912);
  bf16* wob = (bf16*)(ws + 14680064);
  bf16* Qw  = (bf16*)(ws + 16777216);
  bf16* Kw  = (bf16*)(ws + 25165824);
  bf16* Vtw = (bf16*)(ws + 33554432);
  bf16* Ow  = (bf16*)(ws + 41943040);   // total 50331648 B

  k_cvt<<<dim3(2048, 5), 256, 0, stream>>>(x, Wq, Wk, Wv, Wo, xb, wqb, wkb, wvb, wob);
  k_gemm_qkv<<<dim3(32, 24), 256, 0, stream>>>(xb, wqb, wkb, wvb, bq, bk, bv, Qw, Kw, Vtw);
  k_attn<<<dim3(32, 32), 256, 0, stream>>>(Qw, Kw, Vtw, Ow);
  k_gemm_out<<<dim3(32, 8), 256, 0, stream>>>(Ow, wob, bo, out);
}

// Round 3
// 123.736 us; speedup vs baseline: 1.1436x; 1.1436x over previous
//
#include <hip/hip_runtime.h>
#include <hip/hip_bf16.h>
#include <stdint.h>

typedef __bf16 bf16;
typedef __bf16 bf16x8 __attribute__((ext_vector_type(8)));
typedef __bf16 bf16x4 __attribute__((ext_vector_type(4)));
typedef __bf16 bf16x2 __attribute__((ext_vector_type(2)));
typedef float  f32x4  __attribute__((ext_vector_type(4)));
typedef float  f32x16 __attribute__((ext_vector_type(16)));
typedef unsigned int uint;

#define MFMA(a,b,c)   __builtin_amdgcn_mfma_f32_16x16x32_bf16((a),(b),(c),0,0,0)
#define MFMA32(a,b,c) __builtin_amdgcn_mfma_f32_32x32x16_bf16((a),(b),(c),0,0,0)
#define EXP2(x)       __builtin_amdgcn_exp2f(x)

__device__ __forceinline__ void gload_lds16(const void* g, void* lds) {
  __builtin_amdgcn_global_load_lds(
      (const __attribute__((address_space(1))) uint32_t*)g,
      (__attribute__((address_space(3))) uint32_t*)lds, 16, 0, 0);
}

__device__ __forceinline__ uint pk_bf16(float lo, float hi) {
  bf16x2 v; v[0] = (bf16)lo; v[1] = (bf16)hi;
  return __builtin_bit_cast(uint, v);
}

// ---------------- convert fp32 -> bf16 (x + 4 weights) ----------------
__global__ __launch_bounds__(256) void k_cvt(
    const float* __restrict__ x,
    const float* __restrict__ wq, const float* __restrict__ wk,
    const float* __restrict__ wv, const float* __restrict__ wo,
    bf16* __restrict__ xb, bf16* __restrict__ wqb, bf16* __restrict__ wkb,
    bf16* __restrict__ wvb, bf16* __restrict__ wob)
{
  int r = blockIdx.y;
  const float* s; bf16* d; int n;
  switch (r) {
    case 0: s = x;  d = xb;  n = 4194304; break;
    case 1: s = wq; d = wqb; n = 1048576; break;
    case 2: s = wk; d = wkb; n = 1048576; break;
    case 3: s = wv; d = wvb; n = 1048576; break;
    default: s = wo; d = wob; n = 1048576; break;
  }
  int i = (blockIdx.x * 256 + threadIdx.x) * 8;
  if (i >= n) return;
  const float4* sp = (const float4*)(s + i);
  float4 a = sp[0], b = sp[1];
  bf16x8 o;
  o[0]=(bf16)a.x; o[1]=(bf16)a.y; o[2]=(bf16)a.z; o[3]=(bf16)a.w;
  o[4]=(bf16)b.x; o[5]=(bf16)b.y; o[6]=(bf16)b.z; o[7]=(bf16)b.w;
  *(bf16x8*)(d + i) = o;
}

// ---------------- fused QKV projection GEMM ----------------
// Q written scaled by log2(e)/32 into [b,h,n,d]; K into [b,h,n,d]; V into [b,h,d,n].
__global__ __launch_bounds__(256) void k_gemm_qkv(
    const bf16* __restrict__ A,
    const bf16* __restrict__ Wq, const bf16* __restrict__ Wk, const bf16* __restrict__ Wv,
    const float* __restrict__ bq, const float* __restrict__ bk, const float* __restrict__ bv,
    bf16* __restrict__ Qw, bf16* __restrict__ Kw, bf16* __restrict__ Vtw)
{
  __shared__ __align__(16) char As[8192];
  __shared__ __align__(16) char Bs[8192];
  int tid = threadIdx.x;
  int wv4 = tid >> 6, l = tid & 63, lo = l & 15, hi = l >> 4;
  int mt = blockIdx.x;           // 0..31
  int ft = blockIdx.y;           // 0..23
  int wsel = ft >> 3;
  const bf16* W = (wsel == 0) ? Wq : (wsel == 1) ? Wk : Wv;
  const float* bias = (wsel == 0) ? bq : (wsel == 1) ? bk : bv;
  int f0 = (ft & 7) * 128;
  const bf16* Ab = A + (size_t)mt * 128 * 1024;
  const bf16* Wb = W + (size_t)f0 * 1024;
  int wm = wv4 >> 1, wf = wv4 & 1;
  f32x4 acc[4][4];
  #pragma unroll
  for (int i = 0; i < 4; i++)
    #pragma unroll
    for (int j = 0; j < 4; j++) acc[i][j] = (f32x4){0.f, 0.f, 0.f, 0.f};

  for (int k0 = 0; k0 < 1024; k0 += 32) {
    __syncthreads();
    #pragma unroll
    for (int p = 0; p < 2; p++) {
      int e = p * 256 + tid;
      int row = e >> 2, sl = e & 3;
      gload_lds16(Ab + row * 1024 + k0 + sl * 8, As + (p * 256 + wv4 * 64) * 16);
      gload_lds16(Wb + row * 1024 + k0 + sl * 8, Bs + (p * 256 + wv4 * 64) * 16);
    }
    __syncthreads();
    bf16x8 af[4], bfr[4];
    #pragma unroll
    for (int ms = 0; ms < 4; ms++)
      af[ms] = *(const bf16x8*)(As + ((wm * 64 + ms * 16 + lo) * 32 + hi * 8) * 2);
    #pragma unroll
    for (int fs = 0; fs < 4; fs++)
      bfr[fs] = *(const bf16x8*)(Bs + ((wf * 64 + fs * 16 + lo) * 32 + hi * 8) * 2);
    #pragma unroll
    for (int ms = 0; ms < 4; ms++)
      #pragma unroll
      for (int fs = 0; fs < 4; fs++)
        acc[ms][fs] = MFMA(af[ms], bfr[fs], acc[ms][fs]);
  }

  float bv4[4];
  #pragma unroll
  for (int fs = 0; fs < 4; fs++) bv4[fs] = bias[f0 + wf * 64 + fs * 16 + lo];
  #pragma unroll
  for (int ms = 0; ms < 4; ms++) {
    #pragma unroll
    for (int fs = 0; fs < 4; fs++) {
      int fl = f0 + wf * 64 + fs * 16 + lo;
      int h = fl >> 6, dd = fl & 63;
      #pragma unroll
      for (int r = 0; r < 4; r++) {
        int m = mt * 128 + wm * 64 + ms * 16 + hi * 4 + r;
        int b = m >> 11, n = m & 2047;
        float val = acc[ms][fs][r] + bv4[fs];
        if (wsel == 0)      Qw[(((size_t)(b * 16 + h) * 2048 + n) * 64) + dd] = (bf16)(val * 0.0450842199527801f);
        else if (wsel == 1) Kw[(((size_t)(b * 16 + h) * 2048 + n) * 64) + dd] = (bf16)val;
        else                Vtw[(((size_t)(b * 16 + h) * 64 + dd) * 2048) + n] = (bf16)val;
      }
    }
  }
}

// ---------------- flash attention, 32x32 MFMA, in-register P ----------------
// Q pre-scaled by log2(e)/32 (exp2-domain softmax). 4 waves x 32 q-rows.
__global__ __launch_bounds__(256, 2) void k_attn(
    const bf16* __restrict__ Q, const bf16* __restrict__ K,
    const bf16* __restrict__ Vt, bf16* __restrict__ O)
{
  __shared__ __align__(16) char Ks[8192];
  __shared__ __align__(16) char Vs[8192];
  int tid = threadIdx.x;
  int wid = tid >> 6, l = tid & 63;
  int lq = l & 31, hi1 = l >> 5;
  int qt = blockIdx.x, bh = blockIdx.y;
  int qg = qt * 128 + wid * 32 + lq;
  const bf16* Kb = K + (size_t)bh * 2048 * 64;
  const bf16* Vb = Vt + (size_t)bh * 64 * 2048;

  // Q fragments: qf[c][j] = Q[qg][16c + hi1*8 + j]  (B-operand of swapped QK^T)
  bf16x8 qf[4];
  const bf16* Qb = Q + ((size_t)bh * 2048 + qg) * 64 + hi1 * 8;
  #pragma unroll
  for (int c = 0; c < 4; c++) qf[c] = *(const bf16x8*)(Qb + 16 * c);

  f32x16 oacc0, oacc1;
  #pragma unroll
  for (int r = 0; r < 16; r++) { oacc0[r] = 0.f; oacc1[r] = 0.f; }
  float m_run = -1.0e30f, l_run = 0.f;

  int srow = tid >> 3, slot = tid & 7;
  int swz = 16 * (slot ^ (srow & 7));
  uint4 k0r, k1r, v0r, v1r;
  #define STAGE(t) {                                                        \
    k0r = *(const uint4*)(Kb + (size_t)((t)*64 + srow) * 64 + slot * 8);    \
    k1r = *(const uint4*)(Kb + (size_t)((t)*64 + srow + 32) * 64 + slot * 8);\
    v0r = *(const uint4*)(Vb + (size_t)srow * 2048 + (t)*64 + slot * 8);    \
    v1r = *(const uint4*)(Vb + (size_t)(srow + 32) * 2048 + (t)*64 + slot * 8); }

  STAGE(0);
  for (int t = 0; t < 32; ++t) {
    __syncthreads();
    *(uint4*)(Ks + srow * 128 + swz)        = k0r;
    *(uint4*)(Ks + (srow + 32) * 128 + swz) = k1r;
    *(uint4*)(Vs + srow * 128 + swz)        = v0r;
    *(uint4*)(Vs + (srow + 32) * 128 + swz) = v1r;
    __syncthreads();
    if (t < 31) STAGE(t + 1);

    // S^T = K * Q^T : two 32x32 tiles (k 0..31, 32..63), contraction d=64
    f32x16 s0, s1;
    #pragma unroll
    for (int r = 0; r < 16; r++) { s0[r] = 0.f; s1[r] = 0.f; }
    int swk = lq & 7;
    __builtin_amdgcn_s_setprio(1);
    #pragma unroll
    for (int c = 0; c < 4; c++) {
      bf16x8 kf0 = *(const bf16x8*)(Ks + lq * 128 + 16 * ((2*c + hi1) ^ swk));
      s0 = MFMA32(kf0, qf[c], s0);
      bf16x8 kf1 = *(const bf16x8*)(Ks + (32 + lq) * 128 + 16 * ((2*c + hi1) ^ swk));
      s1 = MFMA32(kf1, qf[c], s1);
    }
    __builtin_amdgcn_s_setprio(0);

    // online softmax: lane holds 32 of 64 k-values for q=lq; partner lane^32 the rest
    float tm = fmaxf(s0[0], s1[0]);
    #pragma unroll
    for (int r = 1; r < 16; r++) tm = fmaxf(tm, fmaxf(s0[r], s1[r]));
    tm = fmaxf(tm, __shfl_xor(tm, 32));
    if (!__all(tm <= m_run + 8.0f)) {       // defer-max (T13)
      float mnew = fmaxf(m_run, tm);
      float alpha = EXP2(m_run - mnew);
      l_run *= alpha;
      #pragma unroll
      for (int r = 0; r < 16; r++) { oacc0[r] *= alpha; oacc1[r] *= alpha; }
      m_run = mnew;
    }
    float p0[16], p1[16];
    float tsum = 0.f;
    #pragma unroll
    for (int r = 0; r < 16; r++) { p0[r] = EXP2(s0[r] - m_run); tsum += p0[r]; }
    #pragma unroll
    for (int r = 0; r < 16; r++) { p1[r] = EXP2(s1[r] - m_run); tsum += p1[r]; }
    tsum += __shfl_xor(tsum, 32);
    l_run += tsum;

    // pack P to bf16 + permlane32_swap redistribution (T12) -> PV B-fragments
    uint4 pfrag[4];
    #pragma unroll
    for (int m = 0; m < 2; m++) {
      {
        uint a0 = pk_bf16(p0[8*m+0], p0[8*m+1]);
        uint b0 = pk_bf16(p0[8*m+4], p0[8*m+5]);
        asm volatile("v_permlane32_swap_b32 %0, %1" : "+v"(a0), "+v"(b0));
        uint a1 = pk_bf16(p0[8*m+2], p0[8*m+3]);
        uint b1 = pk_bf16(p0[8*m+6], p0[8*m+7]);
        asm volatile("v_permlane32_swap_b32 %0, %1" : "+v"(a1), "+v"(b1));
        pfrag[m] = (uint4){a0, a1, b0, b1};
      }
      {
        uint a0 = pk_bf16(p1[8*m+0], p1[8*m+1]);
        uint b0 = pk_bf16(p1[8*m+4], p1[8*m+5]);
        asm volatile("v_permlane32_swap_b32 %0, %1" : "+v"(a0), "+v"(b0));
        uint a1 = pk_bf16(p1[8*m+2], p1[8*m+3]);
        uint b1 = pk_bf16(p1[8*m+6], p1[8*m+7]);
        asm volatile("v_permlane32_swap_b32 %0, %1" : "+v"(a1), "+v"(b1));
        pfrag[2 + m] = (uint4){a0, a1, b0, b1};
      }
    }

    // O^T += V^T * P^T : two 32-row d-tiles, contraction k=64 in 4 chunks
    __builtin_amdgcn_s_setprio(1);
    #pragma unroll
    for (int c = 0; c < 4; c++) {
      bf16x8 pf = __builtin_bit_cast(bf16x8, pfrag[c]);
      bf16x8 vf0 = *(const bf16x8*)(Vs + lq * 128 + 16 * ((2*c + hi1) ^ swk));
      oacc0 = MFMA32(vf0, pf, oacc0);
      bf16x8 vf1 = *(const bf16x8*)(Vs + (32 + lq) * 128 + 16 * ((2*c + hi1) ^ swk));
      oacc1 = MFMA32(vf1, pf, oacc1);
    }
    __builtin_amdgcn_s_setprio(0);
  }
  #undef STAGE

  float inv = 1.0f / l_run;
  int b = bh >> 4, h = bh & 15;
  bf16* Ob = O + ((size_t)(b * 2048 + qg)) * 1024 + h * 64 + hi1 * 4;
  #pragma unroll
  for (int g = 0; g < 4; g++) {
    bf16x4 ob;
    #pragma unroll
    for (int j = 0; j < 4; j++) ob[j] = (bf16)(oacc0[4*g+j] * inv);
    *(bf16x4*)(Ob + g * 8) = ob;
  }
  #pragma unroll
  for (int g = 0; g < 4; g++) {
    bf16x4 ob;
    #pragma unroll
    for (int j = 0; j < 4; j++) ob[j] = (bf16)(oacc1[4*g+j] * inv);
    *(bf16x4*)(Ob + 32 + g * 8) = ob;
  }
}

// ---------------- output projection GEMM ----------------
__global__ __launch_bounds__(256) void k_gemm_out(
    const bf16* __restrict__ A,      // O [4096][1024] bf16
    const bf16* __restrict__ W,      // Wo bf16 [1024][1024]
    const float* __restrict__ bias,  // bo
    float* __restrict__ Cout)        // [4096][1024] fp32
{
  __shared__ __align__(16) char As[8192];
  __shared__ __align__(16) char Bs[8192];
  int tid = threadIdx.x;
  int wv4 = tid >> 6, l = tid & 63, lo = l & 15, hi = l >> 4;
  int mt = blockIdx.x;           // 0..31
  int f0 = blockIdx.y * 128;     // 0..7 tiles
  const bf16* Ab = A + (size_t)mt * 128 * 1024;
  const bf16* Wb = W + (size_t)f0 * 1024;
  int wm = wv4 >> 1, wf = wv4 & 1;
  f32x4 acc[4][4];
  #pragma unroll
  for (int i = 0; i < 4; i++)
    #pragma unroll
    for (int j = 0; j < 4; j++) acc[i][j] = (f32x4){0.f, 0.f, 0.f, 0.f};

  for (int k0 = 0; k0 < 1024; k0 += 32) {
    __syncthreads();
    #pragma unroll
    for (int p = 0; p < 2; p++) {
      int e = p * 256 + tid;
      int row = e >> 2, sl = e & 3;
      gload_lds16(Ab + row * 1024 + k0 + sl * 8, As + (p * 256 + wv4 * 64) * 16);
      gload_lds16(Wb + row * 1024 + k0 + sl * 8, Bs + (p * 256 + wv4 * 64) * 16);
    }
    __syncthreads();
    bf16x8 af[4], bfr[4];
    #pragma unroll
    for (int ms = 0; ms < 4; ms++)
      af[ms] = *(const bf16x8*)(As + ((wm * 64 + ms * 16 + lo) * 32 + hi * 8) * 2);
    #pragma unroll
    for (int fs = 0; fs < 4; fs++)
      bfr[fs] = *(const bf16x8*)(Bs + ((wf * 64 + fs * 16 + lo) * 32 + hi * 8) * 2);
    #pragma unroll
    for (int ms = 0; ms < 4; ms++)
      #pragma unroll
      for (int fs = 0; fs < 4; fs++)
        acc[ms][fs] = MFMA(af[ms], bfr[fs], acc[ms][fs]);
  }

  float bv4[4];
  #pragma unroll
  for (int fs = 0; fs < 4; fs++) bv4[fs] = bias[f0 + wf * 64 + fs * 16 + lo];
  #pragma unroll
  for (int ms = 0; ms < 4; ms++)
    #pragma unroll
    for (int fs = 0; fs < 4; fs++) {
      int f = f0 + wf * 64 + fs * 16 + lo;
      #pragma unroll
      for (int r = 0; r < 4; r++) {
        int m = mt * 128 + wm * 64 + ms * 16 + hi * 4 + r;
        Cout[(size_t)m * 1024 + f] = acc[ms][fs][r] + bv4[fs];
      }
    }
}

// ---------------- launch ----------------
extern "C" void kernel_launch(void* const* d_in, const int* in_sizes, int n_in,
                              void* d_out, int out_size, void* d_ws, size_t ws_size,
                              hipStream_t stream) {
  const float* x  = (const float*)d_in[0];
  const float* Wq = (const float*)d_in[1];
  const float* bq = (const float*)d_in[2];
  const float* Wk = (const float*)d_in[3];
  const float* bk = (const float*)d_in[4];
  const float* Wv = (const float*)d_in[5];
  const float* bv = (const float*)d_in[6];
  const float* Wo = (const float*)d_in[7];
  const float* bo = (const float*)d_in[8];
  float* out = (float*)d_out;
  char* ws = (char*)d_ws;

  bf16* xb  = (bf16*)(ws);
  bf16* wqb = (bf16*)(ws + 8388608);
  bf16* wkb = (bf16*)(ws + 10485760);
  bf16* wvb = (bf16*)(ws + 12582912);
  bf16* wob = (bf16*)(ws + 14680064);
  bf16* Qw  = (bf16*)(ws + 16777216);
  bf16* Kw  = (bf16*)(ws + 25165824);
  bf16* Vtw = (bf16*)(ws + 33554432);
  bf16* Ow  = (bf16*)(ws + 41943040);   // total 50331648 B

  k_cvt<<<dim3(2048, 5), 256, 0, stream>>>(x, Wq, Wk, Wv, Wo, xb, wqb, wkb, wvb, wob);
  k_gemm_qkv<<<dim3(32, 24), 256, 0, stream>>>(xb, wqb, wkb, wvb, bq, bk, bv, Qw, Kw, Vtw);
  k_attn<<<dim3(16, 32), 256, 0, stream>>>(Qw, Kw, Vtw, Ow);
  k_gemm_out<<<dim3(32, 8), 256, 0, stream>>>(Ow, wob, bo, out);
}